// Round 1
// 591.425 us; speedup vs baseline: 1.0209x; 1.0209x over previous
//
#include <hip/hip_runtime.h>
#include <stdint.h>

#define NB 8192      // tokens
#define ND 2048      // input dim
#define NO 2048      // output dim
#define NE 8         // experts
#define NT (ND / 32) // 64 K-tiles of 32

typedef __bf16 bf16x8 __attribute__((ext_vector_type(8)));
typedef float floatx4 __attribute__((ext_vector_type(4)));

__device__ __forceinline__ unsigned short f2bf(float f) {
    union { float f; uint32_t u; } v; v.f = f;
    uint32_t u = v.u;
    return (unsigned short)((u + 0x7FFFu + ((u >> 16) & 1u)) >> 16);  // RNE
}

// Convert expert_w fp32 -> bf16 (x is converted inside the router kernel).
__global__ __launch_bounds__(256) void cvt_bf16_kernel(
        const float* __restrict__ b, unsigned short* __restrict__ ob, int n4) {
    int i = blockIdx.x * blockDim.x + threadIdx.x;
    int stride = gridDim.x * blockDim.x;
    for (; i < n4; i += stride) {
        float4 v = ((const float4*)b)[i];
        ushort4 o;
        o.x = f2bf(v.x); o.y = f2bf(v.y); o.z = f2bf(v.z); o.w = f2bf(v.w);
        ((ushort4*)ob)[i] = o;
    }
}

// Phase 1: one wave per token. fp32 logits, top-2 + softmax, AND x->bf16
// (x is already streaming through the wave; write the bf16 copy for free).
__global__ __launch_bounds__(256) void router_topk_kernel(const float* __restrict__ x,
        const float* __restrict__ rw, const float* __restrict__ rb,
        unsigned short* __restrict__ xbf,
        int* __restrict__ i0a, int* __restrict__ i1a,
        float* __restrict__ w0a, float* __restrict__ w1a) {
    const int wave = threadIdx.x >> 6;
    const int lane = threadIdx.x & 63;
    const int t = blockIdx.x * 4 + wave;
    const float4* xp = (const float4*)(x + (size_t)t * ND);
    const float4* rp = (const float4*)rw;
    ushort4* xo = (ushort4*)(xbf + (size_t)t * ND);
    float acc[NE];
#pragma unroll
    for (int e = 0; e < NE; e++) acc[e] = 0.f;
#pragma unroll
    for (int i = 0; i < ND / 256; i++) {   // 8 iters: 64 lanes x float4
        int idx = i * 64 + lane;
        float4 xv = xp[idx];
        ushort4 o;
        o.x = f2bf(xv.x); o.y = f2bf(xv.y); o.z = f2bf(xv.z); o.w = f2bf(xv.w);
        xo[idx] = o;
#pragma unroll
        for (int e = 0; e < NE; e++) {
            float4 rv = rp[(size_t)e * (ND / 4) + idx];
            acc[e] += xv.x * rv.x + xv.y * rv.y + xv.z * rv.z + xv.w * rv.w;
        }
    }
#pragma unroll
    for (int e = 0; e < NE; e++) {
        float v = acc[e];
#pragma unroll
        for (int s = 32; s > 0; s >>= 1) v += __shfl_xor(v, s, 64);
        acc[e] = v;
    }
    if (lane == 0) {
        float lg[NE];
#pragma unroll
        for (int e = 0; e < NE; e++) lg[e] = acc[e] + rb[e];
        int i0 = 0; float v0 = lg[0];
#pragma unroll
        for (int e = 1; e < NE; e++) if (lg[e] > v0) { v0 = lg[e]; i0 = e; }  // first-max ties = top_k
        int i1 = -1; float v1 = -3.4e38f;
#pragma unroll
        for (int e = 0; e < NE; e++) if (e != i0 && lg[e] > v1) { v1 = lg[e]; i1 = e; }
        float ex = expf(v1 - v0);
        float inv = 1.f / (1.f + ex);
        i0a[t] = i0; i1a[t] = i1;
        w0a[t] = inv; w1a[t] = ex * inv;
    }
}

// Phase 2: ballot-compaction into ONE combined list per expert (top-1 and
// top-2 assignments together). A token appears at most once per expert list
// (i0 != i1), so per-expert capacity NB suffices. Order is arbitrary.
__global__ __launch_bounds__(256) void compact_kernel(
        const int* __restrict__ i0a, const int* __restrict__ i1a,
        const float* __restrict__ w0a, const float* __restrict__ w1a,
        int* __restrict__ cnt, int* __restrict__ tok, float* __restrict__ wl) {
    const int lane = threadIdx.x & 63;
    const int gw = (blockIdx.x * 256 + threadIdx.x) >> 6;
    const int t = gw * 64 + lane;
#pragma unroll
    for (int which = 0; which < 2; which++) {
        int sel   = which ? i1a[t] : i0a[t];
        float w   = which ? w1a[t] : w0a[t];
        unsigned long long m[NE];
#pragma unroll
        for (int e = 0; e < NE; e++) m[e] = __ballot(sel == e);
        int slot = __popcll(m[sel] & ((1ull << lane) - 1ull));
        int base = 0;
        if (lane < NE) base = atomicAdd(&cnt[lane], (int)__popcll(m[lane]));
        base = __shfl(base, sel, 64);
        tok[sel * NB + base + slot] = t;
        wl[sel * NB + base + slot]  = w;
    }
}

#define GLL16(g, l) __builtin_amdgcn_global_load_lds( \
    (const __attribute__((address_space(1))) void*)(g), \
    (__attribute__((address_space(3))) void*)(l), 16, 0, 0)

// Gathered 128x128 tile GEMM per expert, bf16 MFMA 16x16x32.
// 2-deep software pipeline: 3 LDS buffers, stage tile t+2 while computing
// tile t, counted vmcnt + raw s_barrier (never drain vmcnt(0) mid-loop).
// The A-gather is L2-miss-heavy (~900 cy); the old 2-barrier structure
// serialized that latency every iteration.
// Output rows collide across experts (each token is in 2 lists) -> out is
// pre-zeroed and the epilogue uses f32 atomicAdd (order-independent).
__global__ __launch_bounds__(256, 3) void moe_gemm_kernel(
        const unsigned short* __restrict__ xbf, const unsigned short* __restrict__ wbf,
        const float* __restrict__ eb, const int* __restrict__ cntArr,
        const int* __restrict__ listTok, const float* __restrict__ listW,
        float* __restrict__ out) {
    __shared__ unsigned short sA[3][128 * 32];
    __shared__ unsigned short sB[3][128 * 32];
    __shared__ int sTok[128];
    __shared__ float sW[128];

    const int e = blockIdx.z, mt = blockIdx.y, nt = blockIdx.x;
    const int cnt = cntArr[e];
    if (mt * 128 >= cnt) return;   // uniform per block: no barrier divergence
    const int tid = threadIdx.x;
    if (tid < 128) {
        int r = mt * 128 + tid;
        bool ok = r < cnt;
        sTok[tid] = ok ? listTok[e * NB + r] : 0;   // row 0 as safe dummy; masked at store
        sW[tid]   = ok ? listW[e * NB + r] : 0.f;
    }
    __syncthreads();

    // staging: 512 chunks of 16B per tile per matrix; 4 GLL16/thread/tile
    const char* gA[2]; const char* gB[2];
    int offAB[2];
#pragma unroll
    for (int r = 0; r < 2; r++) {
        int c = r * 256 + tid;
        int row = c >> 2, colb = (c & 3) * 16;
        gA[r] = (const char*)xbf + (size_t)sTok[row] * (ND * 2) + colb;
        gB[r] = (const char*)wbf + ((size_t)e * NO + (size_t)nt * 128 + row) * (ND * 2) + colb;
        offAB[r] = c * 16;   // byte offset inside one LDS buffer
    }

    const int wave = tid >> 6, lane = tid & 63;
    const int wm = (wave >> 1) * 64, wn = (wave & 1) * 64;   // 2x2 wave grid, 64x64 each
    const int lr = lane & 15, lq = lane >> 4;
    int roA[4], roB[4];
#pragma unroll
    for (int i = 0; i < 4; i++) {
        roA[i] = (wm + i * 16 + lr) * 32 + lq * 8;
        roB[i] = (wn + i * 16 + lr) * 32 + lq * 8;
    }

    floatx4 acc[4][4];
#pragma unroll
    for (int mi = 0; mi < 4; mi++)
#pragma unroll
        for (int nj = 0; nj < 4; nj++) acc[mi][nj] = (floatx4){0.f, 0.f, 0.f, 0.f};

    // prologue: stage tiles 0 and 1 into buffers 0 and 1
#pragma unroll
    for (int r = 0; r < 2; r++) {
        GLL16(gA[r], (char*)sA[0] + offAB[r]);
        GLL16(gB[r], (char*)sB[0] + offAB[r]);
        gA[r] += 64; gB[r] += 64;
    }
#pragma unroll
    for (int r = 0; r < 2; r++) {
        GLL16(gA[r], (char*)sA[1] + offAB[r]);
        GLL16(gB[r], (char*)sB[1] + offAB[r]);
        gA[r] += 64; gB[r] += 64;
    }

    int cur = 0;
#pragma unroll 1
    for (int t = 0; t < NT; t++) {
        int nxt = cur + 2; if (nxt >= 3) nxt -= 3;
        if (t + 2 < NT) {
#pragma unroll
            for (int r = 0; r < 2; r++) {
                GLL16(gA[r], (char*)sA[nxt] + offAB[r]);
                GLL16(gB[r], (char*)sB[nxt] + offAB[r]);
                gA[r] += 64; gB[r] += 64;
            }
            // 12 outstanding -> wait until tile t's 4 oldest have landed
            asm volatile("s_waitcnt vmcnt(8)" ::: "memory");
        } else if (t + 2 == NT) {
            asm volatile("s_waitcnt vmcnt(4)" ::: "memory");
        } else {
            asm volatile("s_waitcnt vmcnt(0)" ::: "memory");
        }
        __builtin_amdgcn_s_barrier();   // all waves: tile t fully in LDS

        const unsigned short* sAc = sA[cur];
        const unsigned short* sBc = sB[cur];
        bf16x8 af[4], bfr[4];
#pragma unroll
        for (int mi = 0; mi < 4; mi++) af[mi] = *(const bf16x8*)&sAc[roA[mi]];
#pragma unroll
        for (int nj = 0; nj < 4; nj++) bfr[nj] = *(const bf16x8*)&sBc[roB[nj]];
#pragma unroll
        for (int mi = 0; mi < 4; mi++)
#pragma unroll
            for (int nj = 0; nj < 4; nj++)
                acc[mi][nj] = __builtin_amdgcn_mfma_f32_16x16x32_bf16(af[mi], bfr[nj], acc[mi][nj], 0, 0, 0);

        // all of this wave's LDS reads of buf[cur] done before the barrier:
        // next iteration stages tile t+3 into this same buffer.
        asm volatile("s_waitcnt lgkmcnt(0)" ::: "memory");
        __builtin_amdgcn_s_barrier();
        cur = cur + 1 == 3 ? 0 : cur + 1;
    }

    // epilogue: C/D layout col=lane&15, row=(lane>>4)*4+reg; atomic combine
#pragma unroll
    for (int nj = 0; nj < 4; nj++) {
        int gn = nt * 128 + wn + nj * 16 + lr;
        float bias = eb[(size_t)e * NO + gn];
#pragma unroll
        for (int mi = 0; mi < 4; mi++) {
#pragma unroll
            for (int r = 0; r < 4; r++) {
                int m = wm + mi * 16 + lq * 4 + r;
                if (mt * 128 + m < cnt) {
                    atomicAdd(out + (size_t)sTok[m] * NO + gn,
                              sW[m] * (acc[mi][nj][r] + bias));
                }
            }
        }
    }
}

extern "C" void kernel_launch(void* const* d_in, const int* in_sizes, int n_in,
                              void* d_out, int out_size, void* d_ws, size_t ws_size,
                              hipStream_t stream) {
    const float* x        = (const float*)d_in[0];
    const float* router_w = (const float*)d_in[1];
    const float* router_b = (const float*)d_in[2];
    const float* expert_w = (const float*)d_in[3];
    const float* expert_b = (const float*)d_in[4];
    float* out = (float*)d_out;
    char* ws = (char*)d_ws;

    unsigned short* xbf = (unsigned short*)ws;                 // 33,554,432 B
    unsigned short* wbf = (unsigned short*)(ws + 33554432);    // 67,108,864 B -> ends 100,663,296
    size_t o = 100663296;
    int*   tokL = (int*)(ws + o);   o += NE * NB * 4;          // combined lists
    float* wL   = (float*)(ws + o); o += NE * NB * 4;
    int*   i0a  = (int*)(ws + o);   o += NB * 4;
    int*   i1a  = (int*)(ws + o);   o += NB * 4;
    float* w0a  = (float*)(ws + o); o += NB * 4;
    float* w1a  = (float*)(ws + o); o += NB * 4;
    int*   cnt  = (int*)(ws + o);   o += 128;

    hipMemsetAsync(cnt, 0, 128, stream);
    hipMemsetAsync(out, 0, (size_t)NB * NO * 4, stream);   // atomic-accumulate base
    router_topk_kernel<<<NB / 4, 256, 0, stream>>>(x, router_w, router_b, xbf,
                                                   i0a, i1a, w0a, w1a);
    cvt_bf16_kernel<<<2048, 256, 0, stream>>>(expert_w, wbf, NE * NO * ND / 4);
    compact_kernel<<<NB / 64 / 4, 256, 0, stream>>>(i0a, i1a, w0a, w1a, cnt, tokL, wL);
    moe_gemm_kernel<<<dim3(NO / 128, NB / 128, NE), 256, 0, stream>>>(
        xbf, wbf, expert_b, cnt, tokL, wL, out);
}